// Round 3
// baseline (77.835 us; speedup 1.0000x reference)
//
#include <hip/hip_runtime.h>

// Regression_55791625175653
// ref: only c3 used. upsample4(nearest) -> 4^3 ones box conv (SAME, lo=1 hi=2)
//      -> softmax over D(192) -> sum(w * arange(192)) -> out [1,256,512] f32.
//
// Separable coarse-cell form per axis: output phase p touches <=2 coarse
// cells with weights  p=0:(j-1,j)*(1,3)  p=1:(j)*(4)  p=2:(j,j+1)*(3,1)
// p=3:(j,j+1)*(2,2);  OOB cells contribute 0 (zero padding).
//
// Layout: block=(64,4). Lanes = 64 consecutive output pixels (each VMEM instr
// touches ONE D-plane, ~2 cache lines). threadIdx.y = D-slice q (12 coarse
// cells each). Per-pixel softmax reduce across the 4 slices via 3 KB LDS.
// 8192 waves -> 32 waves/CU.

#define DC 48
#define HC 64
#define WC 128
#define WOUT 512
#define HOUT 256
#define NPIX (HOUT * WOUT)
#define LOG2E 1.4426950408889634f

__device__ __forceinline__ void axis_weights(int p, int& off, float& w0, float& w1) {
    // p=0: off=-1,(1,3); p=1: off=0,(4,0); p=2: off=0,(3,1); p=3: off=0,(2,2)
    off = (p == 0) ? -1 : 0;
    w0  = (p == 0) ? 1.f : (p == 1) ? 4.f : (p == 2) ? 3.f : 2.f;
    w1  = (p == 0) ? 3.f : (p == 1) ? 0.f : (p == 2) ? 1.f : 2.f;
}

__global__ __launch_bounds__(256)
void regress_kernel(const float* __restrict__ c3, float* __restrict__ out) {
    int x = threadIdx.x;          // 0..63 : pixel lane (wave-contiguous)
    int q = threadIdx.y;          // 0..3  : D-slice (wave-uniform)
    int g = blockIdx.x * 64 + x;  // global pixel id

    int w = g & (WOUT - 1);
    int h = g >> 9;

    int jh = h >> 2, ph = h & 3;
    int jw = w >> 2, pw = w & 3;

    int offh, offw;
    float whA, whB, wwA, wwB;
    axis_weights(ph, offh, whA, whB);
    axis_weights(pw, offw, wwA, wwB);

    int jh0 = jh + offh, jh1 = jh0 + 1;
    float wh0 = (jh0 >= 0 && jh0 < HC) ? whA : 0.f;
    float wh1 = (jh1 < HC) ? whB : 0.f;          // jh1 >= 0 always
    jh0 = (jh0 < 0) ? 0 : jh0;
    jh1 = (jh1 > HC - 1) ? HC - 1 : jh1;

    int jw0 = jw + offw, jw1 = jw0 + 1;
    float ww0 = (jw0 >= 0 && jw0 < WC) ? wwA : 0.f;
    float ww1 = (jw1 < WC) ? wwB : 0.f;
    jw0 = (jw0 < 0) ? 0 : jw0;
    jw1 = (jw1 > WC - 1) ? WC - 1 : jw1;

    // fold log2e: downstream exp uses raw v_exp_f32 (exp2 domain)
    float w00 = wh0 * ww0 * LOG2E, w01 = wh0 * ww1 * LOG2E;
    float w10 = wh1 * ww0 * LOG2E, w11 = wh1 * ww1 * LOG2E;

    int i00 = jh0 * WC + jw0, i01 = jh0 * WC + jw1;
    int i10 = jh1 * WC + jw0, i11 = jh1 * WC + jw1;

    // this wave's coarse-D slice: jd in [12q, 12q+12), plus one-cell halo.
    // jd is wave-uniform -> each load instruction touches a single plane.
    int base = 12 * q;
    float S[14];
    #pragma unroll
    for (int kk = 0; kk < 14; ++kk) {
        int jd  = base - 1 + kk;
        bool ok = (jd >= 0) && (jd < DC);
        int jc  = ok ? jd : 0;
        const float* p = c3 + jc * (HC * WC);
        float val = w00 * p[i00] + w01 * p[i01] + w10 * p[i10] + w11 * p[i11];
        S[kk] = ok ? val : 0.f;
    }

    // pass 1: local max over this slice's 48 conv values (log2 domain)
    float m = -1e30f;
    #pragma unroll
    for (int i = 0; i < 12; ++i) {
        float Sm = S[i], Sc = S[i + 1], Sp = S[i + 2];
        float x0 = Sm + 3.f * Sc;        // d = 4(base+i)+0
        float x1 = 4.f * Sc;             // +1
        float x2 = 3.f * Sc + Sp;        // +2
        float x3 = 2.f * Sc + 2.f * Sp;  // +3
        m = fmaxf(m, fmaxf(fmaxf(x0, x1), fmaxf(x2, x3)));
    }

    // per-pixel max across the 4 D-slices (4 waves of this block)
    __shared__ float lm[4][64];
    __shared__ float ls[4][64];
    __shared__ float lsd[4][64];
    lm[q][x] = m;
    __syncthreads();
    m = fmaxf(fmaxf(lm[0][x], lm[1][x]), fmaxf(lm[2][x], lm[3][x]));

    // pass 2: softmax accumulation + weighted index (exp2 domain)
    float s = 0.f, sd = 0.f;
    #pragma unroll
    for (int i = 0; i < 12; ++i) {
        float Sm = S[i], Sc = S[i + 1], Sp = S[i + 2];
        float x0 = Sm + 3.f * Sc;
        float x1 = 4.f * Sc;
        float x2 = 3.f * Sc + Sp;
        float x3 = 2.f * Sc + 2.f * Sp;
        float e0 = __builtin_amdgcn_exp2f(x0 - m);
        float e1 = __builtin_amdgcn_exp2f(x1 - m);
        float e2 = __builtin_amdgcn_exp2f(x2 - m);
        float e3 = __builtin_amdgcn_exp2f(x3 - m);
        s += e0 + e1 + e2 + e3;
        float d0 = (float)(4 * (base + i));
        sd = fmaf(e0, d0, sd);
        sd = fmaf(e1, d0 + 1.f, sd);
        sd = fmaf(e2, d0 + 2.f, sd);
        sd = fmaf(e3, d0 + 3.f, sd);
    }

    ls[q][x]  = s;
    lsd[q][x] = sd;
    __syncthreads();
    if (q == 0) {
        float st  = (ls[0][x]  + ls[1][x])  + (ls[2][x]  + ls[3][x]);
        float sdt = (lsd[0][x] + lsd[1][x]) + (lsd[2][x] + lsd[3][x]);
        out[g] = sdt / st;
    }
}

extern "C" void kernel_launch(void* const* d_in, const int* in_sizes, int n_in,
                              void* d_out, int out_size, void* d_ws, size_t ws_size,
                              hipStream_t stream) {
    (void)in_sizes; (void)n_in; (void)d_ws; (void)ws_size; (void)out_size;
    const float* c3 = (const float*)d_in[2];   // only c3 is used (inference path)
    float* out = (float*)d_out;
    regress_kernel<<<NPIX / 64, dim3(64, 4), 0, stream>>>(c3, out);
}

// Round 4
// 67.629 us; speedup vs baseline: 1.1509x; 1.1509x over previous
//
#include <hip/hip_runtime.h>

// Regression_55791625175653
// ref: only c3 used. upsample4(nearest) -> 4^3 ones box conv (SAME, lo=1 hi=2)
//      -> softmax over D(192) -> soft-argmin -> out [1,256,512] f32.
//
// Separable coarse-cell form per axis: output phase p touches <=2 coarse
// cells with weights  p=0:(j-1,j)*(1,3)  p=1:(j)*(4)  p=2:(j,j+1)*(3,1)
// p=3:(j,j+1)*(2,2);  OOB cells contribute 0 (zero padding).
//
// Block = 16x16 pixel tile (256 thr). Stage the 6x6x48 coarse subvolume into
// LDS (zeros OOB -> no per-pixel clamping), build shared W-combined
// intermediate B[48][6][16] (separability), then per-pixel H-combine +
// two-pass softargmin in registers. Global loads: 6.75/thread (was 192).

#define DC 48
#define HC 64
#define WC 128
#define WOUT 512
#define HOUT 256
#define LOG2E 1.4426950408889634f

__global__ __launch_bounds__(256)
void regress_kernel(const float* __restrict__ c3, float* __restrict__ out) {
    __shared__ float Ct[DC][6][6];    // coarse tile, zero OOB   (6.9 KB)
    __shared__ float Bt[DC][6][16];   // W-combined intermediate (18 KB)

    int tid = threadIdx.x;
    int bx = blockIdx.x & 31;         // 32 tiles across W
    int by = blockIdx.x >> 5;         // 16 tiles down H
    int W0 = bx * 16, H0 = by * 16;
    int JW0 = bx * 4 - 1, JH0 = by * 4 - 1;

    // ---- stage coarse tile 48 x 6 x 6 (zeros outside volume) ----
    #pragma unroll
    for (int k = 0; k < 7; ++k) {
        int idx = tid + k * 256;
        if (idx < DC * 36) {
            int jd  = idx / 36;
            int rem = idx - jd * 36;
            int r   = rem / 6;
            int c   = rem - r * 6;
            int gh = JH0 + r, gw = JW0 + c;
            bool ok = (gh >= 0) && (gh < HC) && (gw >= 0) && (gw < WC);
            ((float*)Ct)[idx] = ok ? c3[jd * (HC * WC) + gh * WC + gw] : 0.f;
        }
    }
    __syncthreads();

    // ---- B: combine along W per output column x (LOG2E folded here) ----
    #pragma unroll
    for (int k = 0; k < 18; ++k) {
        int idx = tid + k * 256;            // 18*256 == 48*6*16 exactly
        int jd  = idx / 96;
        int rem = idx - jd * 96;
        int r   = rem >> 4;
        int x   = rem & 15;
        int pw  = x & 3;
        int jwA = (x >> 2) + 1 + ((pw == 0) ? -1 : 0);
        float wwA = ((pw == 0) ? 1.f : (pw == 1) ? 4.f : (pw == 2) ? 3.f : 2.f) * LOG2E;
        float wwB = ((pw == 0) ? 3.f : (pw == 1) ? 0.f : (pw == 2) ? 1.f : 2.f) * LOG2E;
        ((float*)Bt)[idx] = wwA * Ct[jd][r][jwA] + wwB * Ct[jd][r][jwA + 1];
    }
    __syncthreads();

    // ---- per-pixel: H-combine into S[48] (registers), then softargmin ----
    int tx = tid & 15, ty = tid >> 4;
    int ph = ty & 3;
    int rA = (ty >> 2) + 1 + ((ph == 0) ? -1 : 0);
    float whA = (ph == 0) ? 1.f : (ph == 1) ? 4.f : (ph == 2) ? 3.f : 2.f;
    float whB = (ph == 0) ? 3.f : (ph == 1) ? 0.f : (ph == 2) ? 1.f : 2.f;

    float S[DC];                      // log2-scaled coarse-D profile
    #pragma unroll
    for (int jd = 0; jd < DC; ++jd)
        S[jd] = whA * Bt[jd][rA][tx] + whB * Bt[jd][rA + 1][tx];

    // pass 1: max over the 192 conv values (exp2 domain)
    float m = -1e30f;
    #pragma unroll
    for (int jd = 0; jd < DC; ++jd) {
        float Sm = (jd == 0) ? 0.f : S[jd - 1];
        float Sc = S[jd];
        float Sp = (jd == DC - 1) ? 0.f : S[jd + 1];
        float x0 = Sm + 3.f * Sc;        // d = 4jd+0
        float x1 = 4.f * Sc;             // +1
        float x2 = 3.f * Sc + Sp;        // +2
        float x3 = 2.f * Sc + 2.f * Sp;  // +3
        m = fmaxf(m, fmaxf(fmaxf(x0, x1), fmaxf(x2, x3)));
    }

    // pass 2: softmax accumulation + weighted index
    float s = 0.f, sd = 0.f;
    #pragma unroll
    for (int jd = 0; jd < DC; ++jd) {
        float Sm = (jd == 0) ? 0.f : S[jd - 1];
        float Sc = S[jd];
        float Sp = (jd == DC - 1) ? 0.f : S[jd + 1];
        float x0 = Sm + 3.f * Sc;
        float x1 = 4.f * Sc;
        float x2 = 3.f * Sc + Sp;
        float x3 = 2.f * Sc + 2.f * Sp;
        float e0 = __builtin_amdgcn_exp2f(x0 - m);
        float e1 = __builtin_amdgcn_exp2f(x1 - m);
        float e2 = __builtin_amdgcn_exp2f(x2 - m);
        float e3 = __builtin_amdgcn_exp2f(x3 - m);
        s += e0 + e1 + e2 + e3;
        float d0 = (float)(4 * jd);
        sd = fmaf(e0, d0, sd);
        sd = fmaf(e1, d0 + 1.f, sd);
        sd = fmaf(e2, d0 + 2.f, sd);
        sd = fmaf(e3, d0 + 3.f, sd);
    }

    out[(H0 + ty) * WOUT + W0 + tx] = sd / s;
}

extern "C" void kernel_launch(void* const* d_in, const int* in_sizes, int n_in,
                              void* d_out, int out_size, void* d_ws, size_t ws_size,
                              hipStream_t stream) {
    (void)in_sizes; (void)n_in; (void)d_ws; (void)ws_size; (void)out_size;
    const float* c3 = (const float*)d_in[2];   // only c3 used (inference path)
    float* out = (float*)d_out;
    regress_kernel<<<(HOUT / 16) * (WOUT / 16), 256, 0, stream>>>(c3, out);
}